// Round 2
// baseline (287.829 us; speedup 1.0000x reference)
//
#include <hip/hip_runtime.h>
#include <hip/hip_bf16.h>

typedef unsigned short u16;
typedef unsigned int   uint;
typedef __attribute__((ext_vector_type(8))) short bf16x8;
typedef __attribute__((ext_vector_type(4))) float f32x4;

constexpr int NELEM = 100;
constexpr int EMBED = 256;
constexpr int HID   = 512;
constexpr int KX    = 306;     // EMBED + 50
constexpr int G     = 50;
constexpr int M     = 64;      // edges (or pair-rows) per block
constexpr int THREADS = 512;   // 8 waves

// frag-ready weight buffers in d_ws (bf16):
//  Wb : [32 nt][10 ks][64 lane][8]  (k==306 row carries b_in; >306 zero)
//  Gb : [32 nt][ 2 ks][64 lane][8]  (g>=50 zero)
//  Ob : [16 slice][64 lane][8]      permuted W_out
//  hpre: [NPAIR][512] f32 (mode 2) or bf16 (mode 1) = emb_table @ W_emb.T
constexpr int WB_ELEMS = 32 * 10 * 64 * 8;   // 163840
constexpr int GB_ELEMS = 32 * 2 * 64 * 8;    // 32768
constexpr int OB_ELEMS = 16 * 64 * 8;        // 8192
constexpr int WEIGHT_ELEMS = WB_ELEMS + GB_ELEMS + OB_ELEMS;   // 204800

__device__ __forceinline__ u16 f2bf(float x) {
    uint u = __float_as_uint(x);
    u = (u + 0x7fffu + ((u >> 16) & 1u)) >> 16;
    return (u16)u;
}
__device__ __forceinline__ uint pk2(float a, float b) {
    __hip_bfloat162 h = __float22bfloat162_rn(make_float2(a, b));
    return *reinterpret_cast<uint*>(&h);
}
__device__ __forceinline__ float bflo(uint u) { return __uint_as_float(u << 16); }
__device__ __forceinline__ float bfhi(uint u) { return __uint_as_float(u & 0xffff0000u); }
__device__ __forceinline__ float silu(float p) {
    return p * __builtin_amdgcn_rcpf(1.f + __expf(-p));
}
__device__ __forceinline__ f32x4 mfma16(bf16x8 a, bf16x8 b, f32x4 c) {
    return __builtin_amdgcn_mfma_f32_16x16x32_bf16(a, b, c, 0, 0, 0);
}

// ---- prep: weight frags (blocks < nprep) + hpre precompute GEMM (rest) -----
__global__ __launch_bounds__(THREADS)
void prep_kernel(const float* __restrict__ W_in,   // [512][306]
                 const float* __restrict__ gate_W, // [512][50]
                 const float* __restrict__ W_out,  // [8][512]
                 const float* __restrict__ b_in,   // [512]
                 const float* __restrict__ table,  // emb f32 [NPAIR][256]
                 u16* __restrict__ Wb,
                 u16* __restrict__ Gb,
                 u16* __restrict__ Ob,
                 float* __restrict__ hpreF,
                 u16*   __restrict__ hpreH,
                 int npair, int nprep, int mode) {
    __shared__ __align__(16) u16 af[8 * 4 * 64 * 8];   // 32 KB A-tile (precompute part)
    const int bid = blockIdx.x;
    const int t   = threadIdx.x;

    if (bid < nprep) {                                  // ---- weight-frag part
        int idx = bid * THREADS + t;
        if (idx < WB_ELEMS) {
            int j = idx & 7, lane = (idx >> 3) & 63, kn = idx >> 9;
            int ks = kn % 10, nt = kn / 10;
            int h = nt * 16 + (lane & 15);
            int k = ks * 32 + (lane >> 4) * 8 + j;
            float v = (k < KX) ? W_in[h * KX + k] : ((k == KX) ? b_in[h] : 0.f);
            Wb[idx] = f2bf(v);
        } else if (idx < WB_ELEMS + GB_ELEMS) {
            int i2 = idx - WB_ELEMS;
            int j = i2 & 7, lane = (i2 >> 3) & 63, kn = i2 >> 9;
            int ks = kn & 1, nt = kn >> 1;
            int h = nt * 16 + (lane & 15);
            int g = ks * 32 + (lane >> 4) * 8 + j;
            Gb[i2] = f2bf((g < G) ? gate_W[h * G + g] : 0.f);
        } else if (idx < WEIGHT_ELEMS) {
            int i2 = idx - WB_ELEMS - GB_ELEMS;
            int j = i2 & 7, lane = (i2 >> 3) & 63, s = i2 >> 9;
            int m = lane & 15, q = lane >> 4;
            int hid = s * 32 + (j >> 2) * 16 + q * 4 + (j & 3);
            Ob[i2] = f2bf((m < 8) ? W_out[m * HID + hid] : 0.f);
        }
        return;
    }

    // ---- precompute: hpre[p][h] = sum_k emb[p][k] * W_in[h][k], k<256 ------
    // Identical MFMA sequence (ks 0..7) to the old fused kernel, so the main
    // kernel's acc-init + ks 8..9 continuation is bit-identical accumulation.
    const int pb = bid - nprep;
    const int p0 = pb * M;
    const int wave = t >> 6, lane = t & 63;
    const int col = lane & 15, quad = lane >> 4;

    // stage A-tile: wave w handles ks = w, mt 0..3 (sequential rows -> coalesced)
    #pragma unroll
    for (int mt = 0; mt < 4; ++mt) {
        int p = p0 + mt * 16 + col;
        uint4 w = {0u, 0u, 0u, 0u};
        if (p < npair) {
            const float* s = table + p * EMBED + wave * 32 + quad * 8;
            float4 v0 = ((const float4*)s)[0], v1 = ((const float4*)s)[1];
            w.x = pk2(v0.x, v0.y); w.y = pk2(v0.z, v0.w);
            w.z = pk2(v1.x, v1.y); w.w = pk2(v1.z, v1.w);
        }
        *(uint4*)&af[((wave * 4 + mt) * 64 + lane) * 8] = w;
    }
    __syncthreads();

    const f32x4 z4 = {0.f, 0.f, 0.f, 0.f};
    #pragma unroll
    for (int nh = 0; nh < 2; ++nh) {
        f32x4 acc[2][4];
        #pragma unroll
        for (int ntl = 0; ntl < 2; ++ntl)
            #pragma unroll
            for (int mt = 0; mt < 4; ++mt) acc[ntl][mt] = z4;
        #pragma unroll 2
        for (int ks = 0; ks < 8; ++ks) {
            bf16x8 a[4];
            #pragma unroll
            for (int mt = 0; mt < 4; ++mt)
                a[mt] = *(const bf16x8*)&af[((ks * 4 + mt) * 64 + lane) * 8];
            #pragma unroll
            for (int ntl = 0; ntl < 2; ++ntl) {
                int h = (wave * 4 + nh * 2 + ntl) * 16 + col;
                int k0 = ks * 32 + quad * 8;
                const float* wsrc = W_in + h * KX + k0;   // 8B-aligned (h*306 even, k0%8==0)
                float2 u0 = ((const float2*)wsrc)[0];
                float2 u1 = ((const float2*)wsrc)[1];
                float2 u2 = ((const float2*)wsrc)[2];
                float2 u3 = ((const float2*)wsrc)[3];
                uint4 wf;
                wf.x = pk2(u0.x, u0.y); wf.y = pk2(u1.x, u1.y);
                wf.z = pk2(u2.x, u2.y); wf.w = pk2(u3.x, u3.y);
                #pragma unroll
                for (int mt = 0; mt < 4; ++mt)
                    acc[ntl][mt] = mfma16(*(bf16x8*)&wf, a[mt], acc[ntl][mt]);
            }
        }
        // store: lane (q,c) holds hpre[p0+mt*16+c][ntg*16 + q*4 + r]
        #pragma unroll
        for (int ntl = 0; ntl < 2; ++ntl)
            #pragma unroll
            for (int mt = 0; mt < 4; ++mt) {
                int p = p0 + mt * 16 + col;
                if (p < npair) {
                    int hb = (wave * 4 + nh * 2 + ntl) * 16 + quad * 4;
                    if (mode == 2) {
                        *(f32x4*)(hpreF + (size_t)p * HID + hb) = acc[ntl][mt];
                    } else {
                        uint2 o;
                        o.x = pk2(acc[ntl][mt][0], acc[ntl][mt][1]);
                        o.y = pk2(acc[ntl][mt][2], acc[ntl][mt][3]);
                        *(uint2*)(hpreH + (size_t)p * HID + hb) = o;
                    }
                }
            }
    }
}

// ---- main kernel: gather hpre row -> acc init; rbf-only GEMM (ks 8..9) -----
template <bool F32H>
__global__ __launch_bounds__(THREADS, 4)
void pair_embed_pre(const int* __restrict__ anum,
                    const int* __restrict__ edge_index,
                    const int* __restrict__ edge_to_src,
                    const float* __restrict__ dist,
                    const float* __restrict__ hpreF,
                    const u16*   __restrict__ hpreH,
                    const float* __restrict__ b_out,
                    const u16* __restrict__ Wb,
                    const u16* __restrict__ Gb,
                    const u16* __restrict__ Ob,
                    float* __restrict__ out,
                    int E) {
    // smem: afrag (rbf A-tile, first 8 KB) unions with redf (full 32 KB).
    // redf needs 8*4*64*4 floats = 8192 f32 = 32 KB -> 16384 u16.
    __shared__ __align__(16) u16 smem[16384];
    __shared__ int   rowbase[M];
    __shared__ float dste[M];
    u16*   afrag = smem;
    float* redf  = (float*)smem;     // [8 wave][4 mt][64 lane][4]

    const int t  = threadIdx.x;
    const int e0 = blockIdx.x * M;
    const int wave = t >> 6, lane = t & 63;
    const int col = lane & 15, quad = lane >> 4;

    if (t < M) {
        int eg = e0 + t;
        int pair = 0; float d = 0.f;
        if (eg < E) {
            int src = edge_to_src[eg];
            pair = anum[edge_index[src]] + NELEM * anum[edge_index[E + src]];
            d = dist[eg];
        }
        rowbase[t] = pair * HID;     // hpre row base (elements)
        dste[t]    = d;
    }
    __syncthreads();

    int rbm[4];
    #pragma unroll
    for (int mt = 0; mt < 4; ++mt) rbm[mt] = rowbase[mt * 16 + col];

    // issue nh=0 hpre gather before rbf staging (latency hides under exp work)
    f32x4 hp[2][4];
    uint2 hph[2][4];
    #pragma unroll
    for (int mt = 0; mt < 4; ++mt) {
        int base = rbm[mt] + (wave * 4) * 16 + quad * 4;
        if (F32H) {
            const float* p = hpreF + base;
            hp[0][mt] = *(const f32x4*)p;
            hp[1][mt] = *(const f32x4*)(p + 16);
        } else {
            const u16* p = hpreH + base;
            hph[0][mt] = *(const uint2*)p;
            hph[1][mt] = *(const uint2*)(p + 16);
        }
    }

    // ---- stage rbf A-tile: wave w -> (ks = w&1, mt = w>>1) -----------------
    {
        const float sp    = 12.0f / 49.0f;
        const float coeff = -0.5f / (sp * sp);
        int ks = wave & 1, mtr = wave >> 1;
        float d  = dste[mtr * 16 + col];
        int   g0 = ks * 32 + quad * 8;
        float f[8];
        #pragma unroll
        for (int j = 0; j < 8; ++j) {
            int g = g0 + j;
            float dd = d - sp * (float)g;
            f[j] = (g < G) ? __expf(coeff * dd * dd) : ((g == G) ? 1.f : 0.f);
        }
        uint4 w;
        w.x = pk2(f[0], f[1]); w.y = pk2(f[2], f[3]);
        w.z = pk2(f[4], f[5]); w.w = pk2(f[6], f[7]);
        *(uint4*)&afrag[((ks * 4 + mtr) * 64 + lane) * 8] = w;
    }
    __syncthreads();

    const f32x4 z4 = {0.f, 0.f, 0.f, 0.f};
    f32x4 oacc[4] = {z4, z4, z4, z4};

    #pragma unroll
    for (int nh = 0; nh < 2; ++nh) {
        if (nh == 1) {                       // gather for 2nd hid half
            #pragma unroll
            for (int mt = 0; mt < 4; ++mt) {
                int base = rbm[mt] + (wave * 4 + 2) * 16 + quad * 4;
                if (F32H) {
                    const float* p = hpreF + base;
                    hp[0][mt] = *(const f32x4*)p;
                    hp[1][mt] = *(const f32x4*)(p + 16);
                } else {
                    const u16* p = hpreH + base;
                    hph[0][mt] = *(const uint2*)p;
                    hph[1][mt] = *(const uint2*)(p + 16);
                }
            }
        }
        f32x4 acc[2][4], gacc[2][4];
        #pragma unroll
        for (int ntl = 0; ntl < 2; ++ntl)
            #pragma unroll
            for (int mt = 0; mt < 4; ++mt) {
                gacc[ntl][mt] = z4;
                if (F32H) {
                    acc[ntl][mt] = hp[ntl][mt];
                } else {
                    uint2 v = hph[ntl][mt];
                    f32x4 a = {bflo(v.x), bfhi(v.x), bflo(v.y), bfhi(v.y)};
                    acc[ntl][mt] = a;
                }
            }

        // merged gate + rbf GEMM over ks 0..1 (A-frags read once)
        const u16* gb = &Gb[((wave * 4 + nh * 2) * 2 * 64 + lane) * 8];
        const u16* wb = &Wb[(((wave * 4 + nh * 2) * 10 + 8) * 64 + lane) * 8];
        #pragma unroll
        for (int ks = 0; ks < 2; ++ks) {
            bf16x8 a[4];
            #pragma unroll
            for (int mt = 0; mt < 4; ++mt)
                a[mt] = *(const bf16x8*)&afrag[((ks * 4 + mt) * 64 + lane) * 8];
            bf16x8 g0f = *(const bf16x8*)&gb[ks * 512];
            bf16x8 w0f = *(const bf16x8*)&wb[ks * 512];
            bf16x8 g1f = *(const bf16x8*)&gb[1024 + ks * 512];
            bf16x8 w1f = *(const bf16x8*)&wb[5120 + ks * 512];
            #pragma unroll
            for (int mt = 0; mt < 4; ++mt) gacc[0][mt] = mfma16(g0f, a[mt], gacc[0][mt]);
            #pragma unroll
            for (int mt = 0; mt < 4; ++mt) acc[0][mt]  = mfma16(w0f, a[mt], acc[0][mt]);
            #pragma unroll
            for (int mt = 0; mt < 4; ++mt) gacc[1][mt] = mfma16(g1f, a[mt], gacc[1][mt]);
            #pragma unroll
            for (int mt = 0; mt < 4; ++mt) acc[1][mt]  = mfma16(w1f, a[mt], acc[1][mt]);
        }

        // silu * gate (f32 gate, no bf16 round-trip) -> out-proj MFMA
        bf16x8 obf = *(const bf16x8*)&Ob[(((wave << 1) | nh) * 64 + lane) * 8];
        #pragma unroll
        for (int mt = 0; mt < 4; ++mt) {
            uint4 hq;
            hq.x = pk2(silu(acc[0][mt][0]) * gacc[0][mt][0],
                       silu(acc[0][mt][1]) * gacc[0][mt][1]);
            hq.y = pk2(silu(acc[0][mt][2]) * gacc[0][mt][2],
                       silu(acc[0][mt][3]) * gacc[0][mt][3]);
            hq.z = pk2(silu(acc[1][mt][0]) * gacc[1][mt][0],
                       silu(acc[1][mt][1]) * gacc[1][mt][1]);
            hq.w = pk2(silu(acc[1][mt][2]) * gacc[1][mt][2],
                       silu(acc[1][mt][3]) * gacc[1][mt][3]);
            oacc[mt] = mfma16(obf, *(bf16x8*)&hq, oacc[mt]);
        }
    }
    __syncthreads();   // afrag reads done; smem becomes red

    #pragma unroll
    for (int mt = 0; mt < 4; ++mt)
        *(f32x4*)&redf[((wave * 4 + mt) * 64 + lane) * 4] = oacc[mt];
    __syncthreads();

    {
        int head = t >> 6, el = t & 63;
        int mt = el >> 4, c = el & 15;
        int l  = (head >> 2) * 16 + c;
        int r  = head & 3;
        float s = 0.f;
        #pragma unroll
        for (int w = 0; w < 8; ++w)
            s += redf[((w * 4 + mt) * 64 + l) * 4 + r];
        int eg = e0 + el;
        if (eg < E) out[head * E + eg] = s + b_out[head];
    }
}

// ---- fallback (ws too small for hpre): previous fused kernel, f32 table ----
__global__ __launch_bounds__(THREADS, 4)
void pair_embed_old(const int* __restrict__ anum,
                    const int* __restrict__ edge_index,
                    const int* __restrict__ edge_to_src,
                    const float* __restrict__ dist,
                    const float* __restrict__ emb_table,
                    const float* __restrict__ b_out,
                    const u16* __restrict__ Wb,
                    const u16* __restrict__ Gb,
                    const u16* __restrict__ Ob,
                    float* __restrict__ out,
                    int E) {
    __shared__ __align__(16) u16 smem[10 * 4 * 64 * 8];
    __shared__ int   rowbase[M];
    __shared__ float dste[M];
    u16*   afrag = smem;
    float* redf  = (float*)smem;

    const int t  = threadIdx.x;
    const int e0 = blockIdx.x * M;
    const int wave = t >> 6, lane = t & 63;
    const int col = lane & 15, quad = lane >> 4;

    if (t < M) {
        int eg = e0 + t;
        int pair = 0; float d = 0.f;
        if (eg < E) {
            int src = edge_to_src[eg];
            pair = anum[edge_index[src]] + NELEM * anum[edge_index[E + src]];
            d = dist[eg];
        }
        rowbase[t] = pair * EMBED;
        dste[t]    = d;
    }
    __syncthreads();

    {
        #pragma unroll 1
        for (int mt = 0; mt < 4; ++mt) {
            int rb = rowbase[mt * 16 + col];
            const float4* src = (const float4*)(emb_table + rb + wave * 32 + quad * 8);
            float4 v0 = src[0], v1 = src[1];
            uint4 w;
            w.x = pk2(v0.x, v0.y); w.y = pk2(v0.z, v0.w);
            w.z = pk2(v1.x, v1.y); w.w = pk2(v1.z, v1.w);
            *(uint4*)&afrag[((wave * 4 + mt) * 64 + lane) * 8] = w;
        }
        {
            const float sp    = 12.0f / 49.0f;
            const float coeff = -0.5f / (sp * sp);
            int ksr = 8 + (wave & 1), mtr = wave >> 1;
            float d  = dste[mtr * 16 + col];
            int   k0 = ksr * 32 + quad * 8;
            float f[8];
            #pragma unroll
            for (int j = 0; j < 8; ++j) {
                int k = k0 + j;
                int g = k - EMBED;
                float dd = d - sp * (float)g;
                f[j] = (g < G) ? __expf(coeff * dd * dd) : ((k == KX) ? 1.f : 0.f);
            }
            uint4 w;
            w.x = pk2(f[0], f[1]); w.y = pk2(f[2], f[3]);
            w.z = pk2(f[4], f[5]); w.w = pk2(f[6], f[7]);
            *(uint4*)&afrag[((ksr * 4 + mtr) * 64 + lane) * 8] = w;
        }
    }
    __syncthreads();

    const f32x4 z4 = {0.f, 0.f, 0.f, 0.f};
    f32x4 oacc[4] = {z4, z4, z4, z4};

    #pragma unroll
    for (int nh = 0; nh < 2; ++nh) {
        uint gp[2][4][2];
        {
            f32x4 gacc[2][4];
            #pragma unroll
            for (int ntl = 0; ntl < 2; ++ntl)
                #pragma unroll
                for (int mt = 0; mt < 4; ++mt) gacc[ntl][mt] = z4;
            #pragma unroll
            for (int ks = 0; ks < 2; ++ks) {
                bf16x8 a[4];
                #pragma unroll
                for (int mt = 0; mt < 4; ++mt)
                    a[mt] = *(const bf16x8*)&afrag[(((8 + ks) * 4 + mt) * 64 + lane) * 8];
                #pragma unroll
                for (int ntl = 0; ntl < 2; ++ntl) {
                    int ntg = wave * 4 + nh * 2 + ntl;
                    bf16x8 g = *(const bf16x8*)&Gb[((ntg * 2 + ks) * 64 + lane) * 8];
                    #pragma unroll
                    for (int mt = 0; mt < 4; ++mt)
                        gacc[ntl][mt] = mfma16(g, a[mt], gacc[ntl][mt]);
                }
            }
            #pragma unroll
            for (int ntl = 0; ntl < 2; ++ntl)
                #pragma unroll
                for (int mt = 0; mt < 4; ++mt) {
                    gp[ntl][mt][0] = pk2(gacc[ntl][mt][0], gacc[ntl][mt][1]);
                    gp[ntl][mt][1] = pk2(gacc[ntl][mt][2], gacc[ntl][mt][3]);
                }
        }

        f32x4 acc[2][4];
        #pragma unroll
        for (int ntl = 0; ntl < 2; ++ntl)
            #pragma unroll
            for (int mt = 0; mt < 4; ++mt) acc[ntl][mt] = z4;
        const u16* wb0 = &Wb[(((wave * 4 + nh * 2 + 0) * 10) * 64 + lane) * 8];
        const u16* wb1 = &Wb[(((wave * 4 + nh * 2 + 1) * 10) * 64 + lane) * 8];
        #pragma unroll 2
        for (int ks = 0; ks < 10; ++ks) {
            bf16x8 a[4];
            #pragma unroll
            for (int mt = 0; mt < 4; ++mt)
                a[mt] = *(const bf16x8*)&afrag[((ks * 4 + mt) * 64 + lane) * 8];
            bf16x8 w0 = *(const bf16x8*)&wb0[ks * 512];
            #pragma unroll
            for (int mt = 0; mt < 4; ++mt)
                acc[0][mt] = mfma16(w0, a[mt], acc[0][mt]);
            bf16x8 w1 = *(const bf16x8*)&wb1[ks * 512];
            #pragma unroll
            for (int mt = 0; mt < 4; ++mt)
                acc[1][mt] = mfma16(w1, a[mt], acc[1][mt]);
        }

        bf16x8 obf = *(const bf16x8*)&Ob[(((wave << 1) | nh) * 64 + lane) * 8];
        #pragma unroll
        for (int mt = 0; mt < 4; ++mt) {
            uint4 hq;
            hq.x = pk2(silu(acc[0][mt][0]) * bflo(gp[0][mt][0]),
                       silu(acc[0][mt][1]) * bfhi(gp[0][mt][0]));
            hq.y = pk2(silu(acc[0][mt][2]) * bflo(gp[0][mt][1]),
                       silu(acc[0][mt][3]) * bfhi(gp[0][mt][1]));
            hq.z = pk2(silu(acc[1][mt][0]) * bflo(gp[1][mt][0]),
                       silu(acc[1][mt][1]) * bfhi(gp[1][mt][0]));
            hq.w = pk2(silu(acc[1][mt][2]) * bflo(gp[1][mt][1]),
                       silu(acc[1][mt][3]) * bfhi(gp[1][mt][1]));
            oacc[mt] = mfma16(obf, *(bf16x8*)&hq, oacc[mt]);
        }
    }
    __syncthreads();

    #pragma unroll
    for (int mt = 0; mt < 4; ++mt)
        *(f32x4*)&redf[((wave * 4 + mt) * 64 + lane) * 4] = oacc[mt];
    __syncthreads();

    {
        int head = t >> 6, el = t & 63;
        int mt = el >> 4, c = el & 15;
        int l  = (head >> 2) * 16 + c;
        int r  = head & 3;
        float s = 0.f;
        #pragma unroll
        for (int w = 0; w < 8; ++w)
            s += redf[((w * 4 + mt) * 64 + l) * 4 + r];
        int eg = e0 + el;
        if (eg < E) out[head * E + eg] = s + b_out[head];
    }
}

extern "C" void kernel_launch(void* const* d_in, const int* in_sizes, int n_in,
                              void* d_out, int out_size, void* d_ws, size_t ws_size,
                              hipStream_t stream) {
    const int*   anum        = (const int*)d_in[0];
    const int*   edge_index  = (const int*)d_in[1];
    const int*   edge_to_src = (const int*)d_in[2];
    const float* dist        = (const float*)d_in[3];
    const float* emb_table   = (const float*)d_in[4];
    const float* gate_W      = (const float*)d_in[5];
    const float* W_in        = (const float*)d_in[6];
    const float* b_in        = (const float*)d_in[7];
    const float* W_out       = (const float*)d_in[8];
    const float* b_out       = (const float*)d_in[9];
    const int E     = in_sizes[3];
    const int TBL   = in_sizes[4];            // NELEM^2 * EMBED elements
    const int NPAIR = TBL / EMBED;

    u16* Wb = (u16*)d_ws;
    u16* Gb = Wb + WB_ELEMS;
    u16* Ob = Gb + GB_ELEMS;
    char* hbase = (char*)d_ws + (size_t)WEIGHT_ELEMS * 2;   // 409600 B, 16B aligned

    const size_t need32 = (size_t)WEIGHT_ELEMS * 2 + (size_t)NPAIR * HID * 4;
    const size_t need16 = (size_t)WEIGHT_ELEMS * 2 + (size_t)NPAIR * HID * 2;
    const int mode = (ws_size >= need32) ? 2 : ((ws_size >= need16) ? 1 : 0);

    const int nprep = (WEIGHT_ELEMS + THREADS - 1) / THREADS;   // 400
    const int npb   = (NPAIR + M - 1) / M;                      // 157
    const int grid  = nprep + (mode ? npb : 0);
    prep_kernel<<<grid, THREADS, 0, stream>>>(
        W_in, gate_W, W_out, b_in, emb_table,
        Wb, Gb, Ob, (float*)hbase, (u16*)hbase, NPAIR, nprep, mode);

    const int nblocks = (E + M - 1) / M;
    if (mode == 2) {
        pair_embed_pre<true><<<nblocks, THREADS, 0, stream>>>(
            anum, edge_index, edge_to_src, dist, (const float*)hbase, (const u16*)hbase,
            b_out, Wb, Gb, Ob, (float*)d_out, E);
    } else if (mode == 1) {
        pair_embed_pre<false><<<nblocks, THREADS, 0, stream>>>(
            anum, edge_index, edge_to_src, dist, (const float*)hbase, (const u16*)hbase,
            b_out, Wb, Gb, Ob, (float*)d_out, E);
    } else {
        pair_embed_old<<<nblocks, THREADS, 0, stream>>>(
            anum, edge_index, edge_to_src, dist, emb_table,
            b_out, Wb, Gb, Ob, (float*)d_out, E);
    }
}